// Round 8
// baseline (429.838 us; speedup 1.0000x reference)
//
#include <hip/hip_runtime.h>

// Problem constants (B,N,F_in,F_out fixed by setup_inputs)
#define NB   4
#define NN   2048
#define FIN  512
#define FOUT 512
#define NHD  8
#define DH   64
#define VTR  520   // Vt rows per batch: 512 data (8 heads x 64 d) + 8 denominator
#define SLOPE 0.2f
#define NBLK 512   // grid: 2 blocks/CU x 256 CUs, co-resident by __launch_bounds__(256,2)

typedef __attribute__((ext_vector_type(8)))  short bhalf8;
typedef __attribute__((ext_vector_type(16))) float f32x16;

__device__ __forceinline__ void load_lds16(const void* g, void* l) {
  __builtin_amdgcn_global_load_lds(
      (const __attribute__((address_space(1))) unsigned int*)g,
      (__attribute__((address_space(3))) unsigned int*)l, 16, 0, 0);
}

// RNE float->bf16 (finite values only in this pipeline)
__device__ __forceinline__ unsigned short bfrne(float x) {
  unsigned int u = __float_as_uint(x);
  return (unsigned short)((u + 0x7FFFu + ((u >> 16) & 1u)) >> 16);
}

// split x,y into bf16 hi (RNE) + bf16 lo (RNE of residual); returns packed pairs
__device__ __forceinline__ void split2(float x, float y,
                                       unsigned int& hp, unsigned int& lp) {
  unsigned int ux = __float_as_uint(x), uy = __float_as_uint(y);
  unsigned int rx = (ux + 0x7FFFu + ((ux >> 16) & 1u)) & 0xFFFF0000u;
  unsigned int ry = (uy + 0x7FFFu + ((uy >> 16) & 1u)) & 0xFFFF0000u;
  float lx = x - __uint_as_float(rx);
  float ly = y - __uint_as_float(ry);
  unsigned int vx = __float_as_uint(lx), vy = __float_as_uint(ly);
  hp = (rx >> 16) | ry;
  lp = ((vx + 0x7FFFu + ((vx >> 16) & 1u)) >> 16)
     | ((vy + 0x7FFFu + ((vy >> 16) & 1u)) & 0xFFFF0000u);
}

// LDS overlay for the four phases (max member ~49 KB)
union SharedMem {
  struct { float s[64][65]; } prep;
  struct {
    unsigned short sAh[128*64], sAl[128*64];
    unsigned short sBh[64*64],  sBl[64*64];
    float erT[128][2];
  } gemm;
  struct { float wm[4]; float wbuf[128]; unsigned short tile[64][136]; } soft;
  struct {
    unsigned short sA[128][72];
    unsigned short sB[2][72*64];
    float denL[128];
  } attn;
};

// Device-scope generation barrier (all NBLK blocks co-resident by construction).
// Release/acquire at agent scope -> correct across non-coherent XCD L2s.
__device__ __forceinline__ void grid_sync(unsigned* bar) {
  __syncthreads();
  if (threadIdx.x == 0) {
    __threadfence();   // release all prior writes to device scope
    unsigned g = __hip_atomic_load(&bar[1], __ATOMIC_RELAXED, __HIP_MEMORY_SCOPE_AGENT);
    unsigned a = __hip_atomic_fetch_add(&bar[0], 1u, __ATOMIC_ACQ_REL, __HIP_MEMORY_SCOPE_AGENT);
    if (a + 1u == (unsigned)NBLK) {
      __hip_atomic_store(&bar[0], 0u, __ATOMIC_RELAXED, __HIP_MEMORY_SCOPE_AGENT);
      __hip_atomic_fetch_add(&bar[1], 1u, __ATOMIC_RELEASE, __HIP_MEMORY_SCOPE_AGENT);
    } else {
      while (__hip_atomic_load(&bar[1], __ATOMIC_ACQUIRE, __HIP_MEMORY_SCOPE_AGENT) == g)
        __builtin_amdgcn_s_sleep(8);
    }
  }
  __syncthreads();
}

// ---------------------------------------------------------------------------
// Single fused kernel: phase0 prep -> phase1 gemm+er -> phase2 softmax/Vt ->
// phase3 attn+epilogue.  Grid 512 x 256.
// ---------------------------------------------------------------------------
__global__ __launch_bounds__(256, 2) void k_fused(
    const float* __restrict__ hin, const int* __restrict__ adj,
    const float* __restrict__ Wr,  const float* __restrict__ av,
    float* __restrict__ out,
    unsigned short* __restrict__ hHi, unsigned short* __restrict__ hLo,
    unsigned short* __restrict__ wTh, unsigned short* __restrict__ wTl,
    float* __restrict__ Whr, float* __restrict__ er,
    unsigned short* __restrict__ Vt, unsigned* __restrict__ bar)
{
  __shared__ SharedMem smem;
  const int tid = threadIdx.x;
  const int bid = blockIdx.x;
  const int lane = tid & 63, wv = tid >> 6;

  // ---------------- Phase 0: h split + Wr transpose/split -----------------
  for (int u = bid; u < 2112; u += NBLK) {
    if (u < 2048) {
      size_t base = ((size_t)u * 256 + tid) * 8;
      float4 a = *(const float4*)(hin + base);
      float4 b = *(const float4*)(hin + base + 4);
      uint4 uh, ul;
      split2(a.x, a.y, uh.x, ul.x);
      split2(a.z, a.w, uh.y, ul.y);
      split2(b.x, b.y, uh.z, ul.z);
      split2(b.z, b.w, uh.w, ul.w);
      *(uint4*)(hHi + base) = uh;
      *(uint4*)(hLo + base) = ul;
    } else {
      auto& s = smem.prep.s;
      const int bid2 = u - 2048;
      const int n0 = (bid2 & 7) * 64, k0 = (bid2 >> 3) * 64;
#pragma unroll
      for (int p = 0; p < 4; ++p) {
        int row = p * 16 + (tid >> 4);
        int col = (tid & 15) * 4;
        float4 v = *(const float4*)(Wr + (size_t)(k0 + row) * FOUT + n0 + col);
        s[row][col] = v.x; s[row][col+1] = v.y; s[row][col+2] = v.z; s[row][col+3] = v.w;
      }
      __syncthreads();
      const int n = tid >> 2;
      const int ks = (tid & 3) * 16;
      uint4 h0, h1, l0, l1;
      split2(s[ks+ 0][n], s[ks+ 1][n], h0.x, l0.x);
      split2(s[ks+ 2][n], s[ks+ 3][n], h0.y, l0.y);
      split2(s[ks+ 4][n], s[ks+ 5][n], h0.z, l0.z);
      split2(s[ks+ 6][n], s[ks+ 7][n], h0.w, l0.w);
      split2(s[ks+ 8][n], s[ks+ 9][n], h1.x, l1.x);
      split2(s[ks+10][n], s[ks+11][n], h1.y, l1.y);
      split2(s[ks+12][n], s[ks+13][n], h1.z, l1.z);
      split2(s[ks+14][n], s[ks+15][n], h1.w, l1.w);
      size_t o = (size_t)(n0 + n) * FIN + k0 + ks;
      *(uint4*)(wTh + o) = h0; *(uint4*)(wTh + o + 8) = h1;
      *(uint4*)(wTl + o) = l0; *(uint4*)(wTl + o + 8) = l1;
    }
  }
  grid_sync(bar);

  // ---------------- Phase 1: Whr = lrelu(h@Wr) + er -----------------------
  {
    auto& S = smem.gemm;
    const int g8 = bid & 7, idx = bid >> 3;     // XCD-grouped
    const int sg = idx >> 3, ct = idx & 7;      // col tiles sweep fastest
    const int c0 = ct * 64;
    const int row0 = (g8 * 8 + sg) * 128;

    const unsigned short* pAh[4]; const unsigned short* pAl[4];
    unsigned short *dAh[4], *dAl[4];
#pragma unroll
    for (int t = 0; t < 4; ++t) {
      int I  = wv + t * 4;
      int rl = I * 8 + (lane >> 3);
      int gk = (lane & 7) ^ (rl & 7);
      pAh[t] = hHi + (size_t)(row0 + rl) * FIN + gk * 8;
      pAl[t] = hLo + (size_t)(row0 + rl) * FIN + gk * 8;
      dAh[t] = S.sAh + I * 512;  dAl[t] = S.sAl + I * 512;
    }
    const unsigned short* pBh[2]; const unsigned short* pBl[2];
    unsigned short *dBh[2], *dBl[2];
#pragma unroll
    for (int t = 0; t < 2; ++t) {
      int I  = wv + t * 4;
      int rl = I * 8 + (lane >> 3);
      int gk = (lane & 7) ^ (rl & 7);
      pBh[t] = wTh + (size_t)(c0 + rl) * FIN + gk * 8;
      pBl[t] = wTl + (size_t)(c0 + rl) * FIN + gk * 8;
      dBh[t] = S.sBh + I * 512;  dBl[t] = S.sBl + I * 512;
    }

    const int wi = wv >> 1, wc = wv & 1;
    const int l31 = lane & 31, half = lane >> 5;
    const int aoff0 = (wi*64 +      l31) * 64;
    const int aoff1 = (wi*64 + 32 + l31) * 64;
    const int boff  = (wc*32 +      l31) * 64;
    f32x16 acc0 = {}; f32x16 acc1 = {};

    for (int k0 = 0; k0 < FIN; k0 += 64) {
#pragma unroll
      for (int t = 0; t < 4; ++t) { load_lds16(pAh[t] + k0, dAh[t]);
                                    load_lds16(pAl[t] + k0, dAl[t]); }
#pragma unroll
      for (int t = 0; t < 2; ++t) { load_lds16(pBh[t] + k0, dBh[t]);
                                    load_lds16(pBl[t] + k0, dBl[t]); }
      __syncthreads();
#pragma unroll
      for (int kb = 0; kb < 4; ++kb) {
        int kg = ((kb*2 + half) ^ (lane & 7)) * 8;
        bhalf8 bh  = *(const bhalf8*)&S.sBh[boff  + kg];
        bhalf8 bl  = *(const bhalf8*)&S.sBl[boff  + kg];
        bhalf8 a0h = *(const bhalf8*)&S.sAh[aoff0 + kg];
        bhalf8 a0l = *(const bhalf8*)&S.sAl[aoff0 + kg];
        bhalf8 a1h = *(const bhalf8*)&S.sAh[aoff1 + kg];
        bhalf8 a1l = *(const bhalf8*)&S.sAl[aoff1 + kg];
        acc0 = __builtin_amdgcn_mfma_f32_32x32x16_bf16(a0h, bh, acc0, 0, 0, 0);
        acc1 = __builtin_amdgcn_mfma_f32_32x32x16_bf16(a1h, bh, acc1, 0, 0, 0);
        acc0 = __builtin_amdgcn_mfma_f32_32x32x16_bf16(a0l, bh, acc0, 0, 0, 0);
        acc1 = __builtin_amdgcn_mfma_f32_32x32x16_bf16(a1l, bh, acc1, 0, 0, 0);
        acc0 = __builtin_amdgcn_mfma_f32_32x32x16_bf16(a0h, bl, acc0, 0, 0, 0);
        acc1 = __builtin_amdgcn_mfma_f32_32x32x16_bf16(a1h, bl, acc1, 0, 0, 0);
      }
      __syncthreads();
    }

    const float a_d = av[wc*32 + l31];
#pragma unroll
    for (int mi = 0; mi < 2; ++mi) {
      const f32x16 a = mi ? acc1 : acc0;
#pragma unroll
      for (int reg = 0; reg < 16; ++reg) {
        int rmap = (reg & 3) + 8*(reg >> 2) + 4*half;
        int rowloc = wi*64 + mi*32 + rmap;
        int grow = row0 + rowloc;
        int b  = grow >> 11;
        int n  = grow & 2047;
        int hd = n >> 8;
        int jj = ((n & 255) << 3) | ct;
        float v = a[reg];
        v = v > 0.f ? v : SLOPE * v;
        Whr[(((size_t)(b*NHD + hd)) * NN + jj) * DH + (wc*32 + l31)] = v;
        float p = v * a_d;
        p += __shfl_xor(p, 16, 32);
        p += __shfl_xor(p,  8, 32);
        p += __shfl_xor(p,  4, 32);
        p += __shfl_xor(p,  2, 32);
        p += __shfl_xor(p,  1, 32);
        if (l31 == 0) S.erT[rowloc][wc] = p;
      }
    }
    __syncthreads();
    if (tid < 128) {
      int grow = row0 + tid;
      int b  = grow >> 11;
      int n  = grow & 2047;
      int hd = n >> 8;
      int jj = ((n & 255) << 3) | ct;
      er[((size_t)(b*NHD + hd)) * NN + jj] = S.erT[tid][0] + S.erT[tid][1];
    }
  }
  grid_sync(bar);

  // ---------------- Phase 2: softmax + Vt build (128-j chunks) ------------
  {
    auto& S = smem.soft;
    const int jc = bid & 15, hh = (bid >> 4) & 7, b = bid >> 7;
    const float* ep = er + ((size_t)(b*NHD + hh)) * NN;
    float m = -1e30f;
    for (int j = tid; j < NN; j += 256) m = fmaxf(m, ep[j]);
#pragma unroll
    for (int off = 32; off; off >>= 1) m = fmaxf(m, __shfl_down(m, off, 64));
    if ((tid & 63) == 0) S.wm[tid >> 6] = m;
    __syncthreads();
    const float mm = fmaxf(fmaxf(S.wm[0], S.wm[1]), fmaxf(S.wm[2], S.wm[3]));
    const int j0 = jc * 128;
    if (tid < 128) {
      float w = expf(ep[j0 + tid] - mm);
      S.wbuf[tid] = w;
      Vt[((size_t)(b*VTR + 512 + hh)) * NN + j0 + tid] = bfrne(w);
    }
    __syncthreads();
    const size_t wbase = ((size_t)(b*NHD + hh)) * NN;
#pragma unroll
    for (int p = 0; p < 8; ++p) {
      int jr = p*16 + (tid >> 4);
      int dc = (tid & 15) * 4;
      float4 v = *(const float4*)(Whr + (wbase + j0 + jr) * DH + dc);
      float wj = S.wbuf[jr];
      S.tile[dc+0][jr] = bfrne(v.x * wj);
      S.tile[dc+1][jr] = bfrne(v.y * wj);
      S.tile[dc+2][jr] = bfrne(v.z * wj);
      S.tile[dc+3][jr] = bfrne(v.w * wj);
    }
    __syncthreads();
#pragma unroll
    for (int q = 0; q < 4; ++q) {
      int idx = q*256 + tid;
      int d = idx >> 4, seg = idx & 15;
      uint4 t16 = *(const uint4*)&S.tile[d][seg*8];
      *(uint4*)(Vt + ((size_t)(b*VTR + hh*64 + d)) * NN + j0 + seg*8) = t16;
    }
  }
  grid_sync(bar);

  // ---------------- Phase 3: attn matmul + epilogue -----------------------
  {
    auto& S = smem.attn;
    const int g8 = bid & 7, rest = bid >> 3;
    const int ct = rest & 7, sg = rest >> 3;
    const int row0 = (g8*8 + sg) * 128;
    const int b = row0 >> 11;

    const unsigned short* pB[3];
    int dOff[3];
#pragma unroll
    for (int t = 0; t < 2; ++t) {
      int I  = wv + t*4;
      int rl = I*8 + (lane >> 3);
      int gk = (lane & 7) ^ (rl & 7);
      pB[t] = Vt + ((size_t)(b*VTR + ct*64 + rl))*NN + gk*8;
      dOff[t] = I*512;
    }
    {
      int x  = lane >> 3;
      int gk = (lane & 7) ^ (x & 7);
      pB[2] = Vt + ((size_t)(b*VTR + 512 + x))*NN + gk*8;
      dOff[2] = 64*64;
    }

    const int* adjp = adj + (size_t)b*NN*NN + (size_t)(row0 & 2047)*NN
                      + (tid >> 3)*NN + (tid & 7)*8;
    unsigned short* sAp = &S.sA[tid >> 3][(tid & 7)*8];

    const int wi = wv >> 1, wc = wv & 1;
    const int l31 = lane & 31, half = lane >> 5;
    f32x16 acc0 = {}; f32x16 acc1 = {}; f32x16 acc2 = {};
    const unsigned short* aRd0 = &S.sA[wi*64 +      l31][half*8];
    const unsigned short* aRd1 = &S.sA[wi*64 + 32 + l31][half*8];
    const int nloc = wc*32 + l31;

    load_lds16(pB[0], &S.sB[0][dOff[0]]);
    load_lds16(pB[1], &S.sB[0][dOff[1]]);
    if (wv == 0) load_lds16(pB[2], &S.sB[0][dOff[2]]);
    int4 q[8];
#pragma unroll
    for (int rr = 0; rr < 4; ++rr) {
      q[2*rr]   = *(const int4*)(adjp + rr*32*NN);
      q[2*rr+1] = *(const int4*)(adjp + rr*32*NN + 4);
    }

    for (int it = 0; it < 32; ++it) {
      const int cur = it & 1;
#pragma unroll
      for (int rr = 0; rr < 4; ++rr) {
        uint4 u;
        u.x = (unsigned)(q[2*rr].x   | (q[2*rr].y   << 16)) * 0x3F80u;
        u.y = (unsigned)(q[2*rr].z   | (q[2*rr].w   << 16)) * 0x3F80u;
        u.z = (unsigned)(q[2*rr+1].x | (q[2*rr+1].y << 16)) * 0x3F80u;
        u.w = (unsigned)(q[2*rr+1].z | (q[2*rr+1].w << 16)) * 0x3F80u;
        *(uint4*)(sAp + rr*32*72) = u;
      }
      __syncthreads();
      if (it < 31) {
        const int nk = (it + 1) * 64;
        unsigned short* nb = S.sB[cur ^ 1];
        load_lds16(pB[0] + nk, nb + dOff[0]);
        load_lds16(pB[1] + nk, nb + dOff[1]);
        if (wv == 0) load_lds16(pB[2] + nk, nb + dOff[2]);
#pragma unroll
        for (int rr = 0; rr < 4; ++rr) {
          q[2*rr]   = *(const int4*)(adjp + rr*32*NN + nk);
          q[2*rr+1] = *(const int4*)(adjp + rr*32*NN + nk + 4);
        }
      }
      const unsigned short* sBc = S.sB[cur];
#pragma unroll
      for (int kb = 0; kb < 4; ++kb) {
        int kg = (kb*2 + half) ^ (lane & 7);
        bhalf8 bf  = *(const bhalf8*)&sBc[nloc*64 + kg*8];
        bhalf8 bf2 = {};
        if (l31 < 8) bf2 = *(const bhalf8*)&sBc[(64 + l31)*64 + kg*8];
        bhalf8 a0 = *(const bhalf8*)(aRd0 + kb*16);
        bhalf8 a1 = *(const bhalf8*)(aRd1 + kb*16);
        acc0 = __builtin_amdgcn_mfma_f32_32x32x16_bf16(a0, bf,  acc0, 0, 0, 0);
        acc1 = __builtin_amdgcn_mfma_f32_32x32x16_bf16(a1, bf,  acc1, 0, 0, 0);
        acc2 = __builtin_amdgcn_mfma_f32_32x32x16_bf16(wc ? a1 : a0, bf2, acc2, 0, 0, 0);
      }
      __syncthreads();
    }
    if (l31 == ct) {
#pragma unroll
      for (int reg = 0; reg < 16; ++reg)
        S.denL[wv*32 + (reg & 3) + 8*(reg >> 2) + 4*half] = acc2[reg];
    }
    __syncthreads();
    const int ib = row0 & 2047;
#pragma unroll
    for (int mi = 0; mi < 2; ++mi) {
      const f32x16 a = mi ? acc1 : acc0;
#pragma unroll
      for (int reg = 0; reg < 16; ++reg) {
        int il = wi*64 + mi*32 + (reg & 3) + 8*(reg >> 2) + 4*half;
        int i  = ib + il;
        float v = a[reg] / S.denL[il];
        v = v > 0.f ? v : expm1f(v);
        int n = (ct << 8) | (i >> 3);
        int f = ((i & 7) << 6) | nloc;
        out[((size_t)b*NN + n)*FOUT + f] = v;
      }
    }
  }
}

// ---------------------------------------------------------------------------
extern "C" void kernel_launch(void* const* d_in, const int* in_sizes, int n_in,
                              void* d_out, int out_size, void* d_ws, size_t ws_size,
                              hipStream_t stream)
{
  const float* hin = (const float*)d_in[0];   // h   f32 [4,2048,512]
  const int*   adj = (const int*)d_in[1];     // adj int32 [4,2048,2048]
  // d_in[2] = W_l : mathematically dead (softmax(el[i]+er[j]) == softmax(er[j]))
  const float* Wr  = (const float*)d_in[3];   // W_r f32 [512,512]
  const float* av  = (const float*)d_in[4];   // a   f32 [64,1]
  float* out = (float*)d_out;

  // Workspace overlays (peak ~34.9 MB):
  //   [0, 8.39M)      hHi   -> dead after phase1; overlaid by Vt
  //   [8.39M,16.78M)  hLo   -> dead after phase1
  //   [16.78M,17.30M) wTh   -> dead after phase1
  //   [17.30M,17.83M) wTl   -> dead after phase1
  //   [17.83M,34.60M) Whr (f32)
  //   [34.60M,34.86M) er
  //   [34.86M,+8B)    barrier counters (zeroed each call)
  //   [0, 8.52M)      Vt (bf16, 520 rows/batch) after phase1
  char* ws = (char*)d_ws;
  unsigned short* hHi = (unsigned short*)(ws);
  unsigned short* hLo = (unsigned short*)(ws + 8388608);
  unsigned short* wTh = (unsigned short*)(ws + 16777216);
  unsigned short* wTl = (unsigned short*)(ws + 17301504);
  float* Whr  = (float*)(ws + 17825792);
  float* er   = (float*)(ws + 34603008);
  unsigned short* Vt = (unsigned short*)(ws);
  unsigned* bar = (unsigned*)(ws + 34865152);

  hipMemsetAsync(bar, 0, 8, stream);
  k_fused<<<dim3(NBLK), dim3(256), 0, stream>>>(
      hin, adj, Wr, av, out, hHi, hLo, wTh, wTl, Whr, er, Vt, bar);
}

// Round 9
// 371.816 us; speedup vs baseline: 1.1560x; 1.1560x over previous
//
#include <hip/hip_runtime.h>

// Problem constants (B,N,F_in,F_out fixed by setup_inputs)
#define NB   4
#define NN   2048
#define FIN  512
#define FOUT 512
#define NHD  8
#define DH   64
#define VTR  520   // Vt rows per batch: 512 data (8 heads x 64 d) + 8 denominator
#define SLOPE 0.2f
#define NBLK 512   // grid: 2 blocks/CU x 256 CUs, co-resident by __launch_bounds__(256,2)

typedef __attribute__((ext_vector_type(8)))  short bhalf8;
typedef __attribute__((ext_vector_type(16))) float f32x16;

__device__ __forceinline__ void load_lds16(const void* g, void* l) {
  __builtin_amdgcn_global_load_lds(
      (const __attribute__((address_space(1))) unsigned int*)g,
      (__attribute__((address_space(3))) unsigned int*)l, 16, 0, 0);
}

// RNE float->bf16 (finite values only in this pipeline)
__device__ __forceinline__ unsigned short bfrne(float x) {
  unsigned int u = __float_as_uint(x);
  return (unsigned short)((u + 0x7FFFu + ((u >> 16) & 1u)) >> 16);
}

// split x,y into bf16 hi (RNE) + bf16 lo (RNE of residual); returns packed pairs
__device__ __forceinline__ void split2(float x, float y,
                                       unsigned int& hp, unsigned int& lp) {
  unsigned int ux = __float_as_uint(x), uy = __float_as_uint(y);
  unsigned int rx = (ux + 0x7FFFu + ((ux >> 16) & 1u)) & 0xFFFF0000u;
  unsigned int ry = (uy + 0x7FFFu + ((uy >> 16) & 1u)) & 0xFFFF0000u;
  float lx = x - __uint_as_float(rx);
  float ly = y - __uint_as_float(ry);
  unsigned int vx = __float_as_uint(lx), vy = __float_as_uint(ly);
  hp = (rx >> 16) | ry;
  lp = ((vx + 0x7FFFu + ((vx >> 16) & 1u)) >> 16)
     | ((vy + 0x7FFFu + ((vy >> 16) & 1u)) & 0xFFFF0000u);
}

// LDS overlay for the four phases (max member ~49 KB)
union SharedMem {
  struct { float s[64][65]; } prep;
  struct {
    unsigned short sAh[128*64], sAl[128*64];
    unsigned short sBh[64*64],  sBl[64*64];
    float erT[128][2];
  } gemm;
  struct { float wm[4]; float wbuf[128]; unsigned short tile[64][136]; } soft;
  struct {
    unsigned short sA[128][72];
    unsigned short sB[2][72*64];
    float denL[128];
  } attn;
};

// Device-scope generation barrier, invalidation-storm-free:
//  - waiters poll RELAXED (agent-scope atomics read the coherent point without
//    per-poll cache invalidates) with s_sleep backoff;
//  - exactly ONE release fence before arrival and ONE acquire fence after the
//    generation flip, per block per barrier;
//  - releaser fences between reading the last arrival and flipping the flag,
//    so all blocks' write-backs happen-before the flip (fence-fence sync).
__device__ __forceinline__ void grid_sync(unsigned* bar) {
  __syncthreads();
  if (threadIdx.x == 0) {
    __threadfence();   // release: write back this block's phase output
    unsigned g = __hip_atomic_load(&bar[1], __ATOMIC_RELAXED, __HIP_MEMORY_SCOPE_AGENT);
    unsigned a = __hip_atomic_fetch_add(&bar[0], 1u, __ATOMIC_RELAXED, __HIP_MEMORY_SCOPE_AGENT);
    if (a + 1u == (unsigned)NBLK) {
      __hip_atomic_store(&bar[0], 0u, __ATOMIC_RELAXED, __HIP_MEMORY_SCOPE_AGENT);
      __threadfence(); // order all arrivals' write-backs before the flip
      __hip_atomic_store(&bar[1], g + 1u, __ATOMIC_RELAXED, __HIP_MEMORY_SCOPE_AGENT);
    } else {
      while (__hip_atomic_load(&bar[1], __ATOMIC_RELAXED, __HIP_MEMORY_SCOPE_AGENT) == g)
        __builtin_amdgcn_s_sleep(32);
    }
    __threadfence();   // acquire: single invalidate, then read the next phase
  }
  __syncthreads();
}

// ---------------------------------------------------------------------------
// Single fused kernel: phase0 prep -> phase1 gemm+er -> phase2 softmax/Vt ->
// phase3 attn+epilogue.  Grid 512 x 256.
// ---------------------------------------------------------------------------
__global__ __launch_bounds__(256, 2) void k_fused(
    const float* __restrict__ hin, const int* __restrict__ adj,
    const float* __restrict__ Wr,  const float* __restrict__ av,
    float* __restrict__ out,
    unsigned short* __restrict__ hHi, unsigned short* __restrict__ hLo,
    unsigned short* __restrict__ wTh, unsigned short* __restrict__ wTl,
    float* __restrict__ Whr, float* __restrict__ er,
    unsigned short* __restrict__ Vt, unsigned* __restrict__ bar)
{
  __shared__ SharedMem smem;
  const int tid = threadIdx.x;
  const int bid = blockIdx.x;
  const int lane = tid & 63, wv = tid >> 6;

  // ---------------- Phase 0: h split + Wr transpose/split -----------------
  for (int u = bid; u < 2112; u += NBLK) {
    if (u < 2048) {
      size_t base = ((size_t)u * 256 + tid) * 8;
      float4 a = *(const float4*)(hin + base);
      float4 b = *(const float4*)(hin + base + 4);
      uint4 uh, ul;
      split2(a.x, a.y, uh.x, ul.x);
      split2(a.z, a.w, uh.y, ul.y);
      split2(b.x, b.y, uh.z, ul.z);
      split2(b.z, b.w, uh.w, ul.w);
      *(uint4*)(hHi + base) = uh;
      *(uint4*)(hLo + base) = ul;
    } else {
      auto& s = smem.prep.s;
      const int bid2 = u - 2048;
      const int n0 = (bid2 & 7) * 64, k0 = (bid2 >> 3) * 64;
#pragma unroll
      for (int p = 0; p < 4; ++p) {
        int row = p * 16 + (tid >> 4);
        int col = (tid & 15) * 4;
        float4 v = *(const float4*)(Wr + (size_t)(k0 + row) * FOUT + n0 + col);
        s[row][col] = v.x; s[row][col+1] = v.y; s[row][col+2] = v.z; s[row][col+3] = v.w;
      }
      __syncthreads();
      const int n = tid >> 2;
      const int ks = (tid & 3) * 16;
      uint4 h0, h1, l0, l1;
      split2(s[ks+ 0][n], s[ks+ 1][n], h0.x, l0.x);
      split2(s[ks+ 2][n], s[ks+ 3][n], h0.y, l0.y);
      split2(s[ks+ 4][n], s[ks+ 5][n], h0.z, l0.z);
      split2(s[ks+ 6][n], s[ks+ 7][n], h0.w, l0.w);
      split2(s[ks+ 8][n], s[ks+ 9][n], h1.x, l1.x);
      split2(s[ks+10][n], s[ks+11][n], h1.y, l1.y);
      split2(s[ks+12][n], s[ks+13][n], h1.z, l1.z);
      split2(s[ks+14][n], s[ks+15][n], h1.w, l1.w);
      size_t o = (size_t)(n0 + n) * FIN + k0 + ks;
      *(uint4*)(wTh + o) = h0; *(uint4*)(wTh + o + 8) = h1;
      *(uint4*)(wTl + o) = l0; *(uint4*)(wTl + o + 8) = l1;
    }
  }
  grid_sync(bar);

  // ---------------- Phase 1: Whr = lrelu(h@Wr) + er -----------------------
  {
    auto& S = smem.gemm;
    const int g8 = bid & 7, idx = bid >> 3;     // XCD-grouped
    const int sg = idx >> 3, ct = idx & 7;      // col tiles sweep fastest
    const int c0 = ct * 64;
    const int row0 = (g8 * 8 + sg) * 128;

    const unsigned short* pAh[4]; const unsigned short* pAl[4];
    unsigned short *dAh[4], *dAl[4];
#pragma unroll
    for (int t = 0; t < 4; ++t) {
      int I  = wv + t * 4;
      int rl = I * 8 + (lane >> 3);
      int gk = (lane & 7) ^ (rl & 7);
      pAh[t] = hHi + (size_t)(row0 + rl) * FIN + gk * 8;
      pAl[t] = hLo + (size_t)(row0 + rl) * FIN + gk * 8;
      dAh[t] = S.sAh + I * 512;  dAl[t] = S.sAl + I * 512;
    }
    const unsigned short* pBh[2]; const unsigned short* pBl[2];
    unsigned short *dBh[2], *dBl[2];
#pragma unroll
    for (int t = 0; t < 2; ++t) {
      int I  = wv + t * 4;
      int rl = I * 8 + (lane >> 3);
      int gk = (lane & 7) ^ (rl & 7);
      pBh[t] = wTh + (size_t)(c0 + rl) * FIN + gk * 8;
      pBl[t] = wTl + (size_t)(c0 + rl) * FIN + gk * 8;
      dBh[t] = S.sBh + I * 512;  dBl[t] = S.sBl + I * 512;
    }

    const int wi = wv >> 1, wc = wv & 1;
    const int l31 = lane & 31, half = lane >> 5;
    const int aoff0 = (wi*64 +      l31) * 64;
    const int aoff1 = (wi*64 + 32 + l31) * 64;
    const int boff  = (wc*32 +      l31) * 64;
    f32x16 acc0 = {}; f32x16 acc1 = {};

    for (int k0 = 0; k0 < FIN; k0 += 64) {
#pragma unroll
      for (int t = 0; t < 4; ++t) { load_lds16(pAh[t] + k0, dAh[t]);
                                    load_lds16(pAl[t] + k0, dAl[t]); }
#pragma unroll
      for (int t = 0; t < 2; ++t) { load_lds16(pBh[t] + k0, dBh[t]);
                                    load_lds16(pBl[t] + k0, dBl[t]); }
      __syncthreads();
#pragma unroll
      for (int kb = 0; kb < 4; ++kb) {
        int kg = ((kb*2 + half) ^ (lane & 7)) * 8;
        bhalf8 bh  = *(const bhalf8*)&S.sBh[boff  + kg];
        bhalf8 bl  = *(const bhalf8*)&S.sBl[boff  + kg];
        bhalf8 a0h = *(const bhalf8*)&S.sAh[aoff0 + kg];
        bhalf8 a0l = *(const bhalf8*)&S.sAl[aoff0 + kg];
        bhalf8 a1h = *(const bhalf8*)&S.sAh[aoff1 + kg];
        bhalf8 a1l = *(const bhalf8*)&S.sAl[aoff1 + kg];
        acc0 = __builtin_amdgcn_mfma_f32_32x32x16_bf16(a0h, bh, acc0, 0, 0, 0);
        acc1 = __builtin_amdgcn_mfma_f32_32x32x16_bf16(a1h, bh, acc1, 0, 0, 0);
        acc0 = __builtin_amdgcn_mfma_f32_32x32x16_bf16(a0l, bh, acc0, 0, 0, 0);
        acc1 = __builtin_amdgcn_mfma_f32_32x32x16_bf16(a1l, bh, acc1, 0, 0, 0);
        acc0 = __builtin_amdgcn_mfma_f32_32x32x16_bf16(a0h, bl, acc0, 0, 0, 0);
        acc1 = __builtin_amdgcn_mfma_f32_32x32x16_bf16(a1h, bl, acc1, 0, 0, 0);
      }
      __syncthreads();
    }

    const float a_d = av[wc*32 + l31];
#pragma unroll
    for (int mi = 0; mi < 2; ++mi) {
      const f32x16 a = mi ? acc1 : acc0;
#pragma unroll
      for (int reg = 0; reg < 16; ++reg) {
        int rmap = (reg & 3) + 8*(reg >> 2) + 4*half;
        int rowloc = wi*64 + mi*32 + rmap;
        int grow = row0 + rowloc;
        int b  = grow >> 11;
        int n  = grow & 2047;
        int hd = n >> 8;
        int jj = ((n & 255) << 3) | ct;
        float v = a[reg];
        v = v > 0.f ? v : SLOPE * v;
        Whr[(((size_t)(b*NHD + hd)) * NN + jj) * DH + (wc*32 + l31)] = v;
        float p = v * a_d;
        p += __shfl_xor(p, 16, 32);
        p += __shfl_xor(p,  8, 32);
        p += __shfl_xor(p,  4, 32);
        p += __shfl_xor(p,  2, 32);
        p += __shfl_xor(p,  1, 32);
        if (l31 == 0) S.erT[rowloc][wc] = p;
      }
    }
    __syncthreads();
    if (tid < 128) {
      int grow = row0 + tid;
      int b  = grow >> 11;
      int n  = grow & 2047;
      int hd = n >> 8;
      int jj = ((n & 255) << 3) | ct;
      er[((size_t)(b*NHD + hd)) * NN + jj] = S.erT[tid][0] + S.erT[tid][1];
    }
  }
  grid_sync(bar);

  // ---------------- Phase 2: softmax + Vt build (128-j chunks) ------------
  {
    auto& S = smem.soft;
    const int jc = bid & 15, hh = (bid >> 4) & 7, b = bid >> 7;
    const float* ep = er + ((size_t)(b*NHD + hh)) * NN;
    float m = -1e30f;
    for (int j = tid; j < NN; j += 256) m = fmaxf(m, ep[j]);
#pragma unroll
    for (int off = 32; off; off >>= 1) m = fmaxf(m, __shfl_down(m, off, 64));
    if ((tid & 63) == 0) S.wm[tid >> 6] = m;
    __syncthreads();
    const float mm = fmaxf(fmaxf(S.wm[0], S.wm[1]), fmaxf(S.wm[2], S.wm[3]));
    const int j0 = jc * 128;
    if (tid < 128) {
      float w = expf(ep[j0 + tid] - mm);
      S.wbuf[tid] = w;
      Vt[((size_t)(b*VTR + 512 + hh)) * NN + j0 + tid] = bfrne(w);
    }
    __syncthreads();
    const size_t wbase = ((size_t)(b*NHD + hh)) * NN;
#pragma unroll
    for (int p = 0; p < 8; ++p) {
      int jr = p*16 + (tid >> 4);
      int dc = (tid & 15) * 4;
      float4 v = *(const float4*)(Whr + (wbase + j0 + jr) * DH + dc);
      float wj = S.wbuf[jr];
      S.tile[dc+0][jr] = bfrne(v.x * wj);
      S.tile[dc+1][jr] = bfrne(v.y * wj);
      S.tile[dc+2][jr] = bfrne(v.z * wj);
      S.tile[dc+3][jr] = bfrne(v.w * wj);
    }
    __syncthreads();
#pragma unroll
    for (int q = 0; q < 4; ++q) {
      int idx = q*256 + tid;
      int d = idx >> 4, seg = idx & 15;
      uint4 t16 = *(const uint4*)&S.tile[d][seg*8];
      *(uint4*)(Vt + ((size_t)(b*VTR + hh*64 + d)) * NN + j0 + seg*8) = t16;
    }
  }
  grid_sync(bar);

  // ---------------- Phase 3: attn matmul + epilogue -----------------------
  {
    auto& S = smem.attn;
    const int g8 = bid & 7, rest = bid >> 3;
    const int ct = rest & 7, sg = rest >> 3;
    const int row0 = (g8*8 + sg) * 128;
    const int b = row0 >> 11;

    const unsigned short* pB[3];
    int dOff[3];
#pragma unroll
    for (int t = 0; t < 2; ++t) {
      int I  = wv + t*4;
      int rl = I*8 + (lane >> 3);
      int gk = (lane & 7) ^ (rl & 7);
      pB[t] = Vt + ((size_t)(b*VTR + ct*64 + rl))*NN + gk*8;
      dOff[t] = I*512;
    }
    {
      int x  = lane >> 3;
      int gk = (lane & 7) ^ (x & 7);
      pB[2] = Vt + ((size_t)(b*VTR + 512 + x))*NN + gk*8;
      dOff[2] = 64*64;
    }

    const int* adjp = adj + (size_t)b*NN*NN + (size_t)(row0 & 2047)*NN
                      + (tid >> 3)*NN + (tid & 7)*8;
    unsigned short* sAp = &S.sA[tid >> 3][(tid & 7)*8];

    const int wi = wv >> 1, wc = wv & 1;
    const int l31 = lane & 31, half = lane >> 5;
    f32x16 acc0 = {}; f32x16 acc1 = {}; f32x16 acc2 = {};
    const unsigned short* aRd0 = &S.sA[wi*64 +      l31][half*8];
    const unsigned short* aRd1 = &S.sA[wi*64 + 32 + l31][half*8];
    const int nloc = wc*32 + l31;

    load_lds16(pB[0], &S.sB[0][dOff[0]]);
    load_lds16(pB[1], &S.sB[0][dOff[1]]);
    if (wv == 0) load_lds16(pB[2], &S.sB[0][dOff[2]]);
    int4 q[8];
#pragma unroll
    for (int rr = 0; rr < 4; ++rr) {
      q[2*rr]   = *(const int4*)(adjp + rr*32*NN);
      q[2*rr+1] = *(const int4*)(adjp + rr*32*NN + 4);
    }

    for (int it = 0; it < 32; ++it) {
      const int cur = it & 1;
#pragma unroll
      for (int rr = 0; rr < 4; ++rr) {
        uint4 u;
        u.x = (unsigned)(q[2*rr].x   | (q[2*rr].y   << 16)) * 0x3F80u;
        u.y = (unsigned)(q[2*rr].z   | (q[2*rr].w   << 16)) * 0x3F80u;
        u.z = (unsigned)(q[2*rr+1].x | (q[2*rr+1].y << 16)) * 0x3F80u;
        u.w = (unsigned)(q[2*rr+1].z | (q[2*rr+1].w << 16)) * 0x3F80u;
        *(uint4*)(sAp + rr*32*72) = u;
      }
      __syncthreads();
      if (it < 31) {
        const int nk = (it + 1) * 64;
        unsigned short* nb = S.sB[cur ^ 1];
        load_lds16(pB[0] + nk, nb + dOff[0]);
        load_lds16(pB[1] + nk, nb + dOff[1]);
        if (wv == 0) load_lds16(pB[2] + nk, nb + dOff[2]);
#pragma unroll
        for (int rr = 0; rr < 4; ++rr) {
          q[2*rr]   = *(const int4*)(adjp + rr*32*NN + nk);
          q[2*rr+1] = *(const int4*)(adjp + rr*32*NN + nk + 4);
        }
      }
      const unsigned short* sBc = S.sB[cur];
#pragma unroll
      for (int kb = 0; kb < 4; ++kb) {
        int kg = (kb*2 + half) ^ (lane & 7);
        bhalf8 bf  = *(const bhalf8*)&sBc[nloc*64 + kg*8];
        bhalf8 bf2 = {};
        if (l31 < 8) bf2 = *(const bhalf8*)&sBc[(64 + l31)*64 + kg*8];
        bhalf8 a0 = *(const bhalf8*)(aRd0 + kb*16);
        bhalf8 a1 = *(const bhalf8*)(aRd1 + kb*16);
        acc0 = __builtin_amdgcn_mfma_f32_32x32x16_bf16(a0, bf,  acc0, 0, 0, 0);
        acc1 = __builtin_amdgcn_mfma_f32_32x32x16_bf16(a1, bf,  acc1, 0, 0, 0);
        acc2 = __builtin_amdgcn_mfma_f32_32x32x16_bf16(wc ? a1 : a0, bf2, acc2, 0, 0, 0);
      }
      __syncthreads();
    }
    if (l31 == ct) {
#pragma unroll
      for (int reg = 0; reg < 16; ++reg)
        S.denL[wv*32 + (reg & 3) + 8*(reg >> 2) + 4*half] = acc2[reg];
    }
    __syncthreads();
    const int ib = row0 & 2047;
#pragma unroll
    for (int mi = 0; mi < 2; ++mi) {
      const f32x16 a = mi ? acc1 : acc0;
#pragma unroll
      for (int reg = 0; reg < 16; ++reg) {
        int il = wi*64 + mi*32 + (reg & 3) + 8*(reg >> 2) + 4*half;
        int i  = ib + il;
        float v = a[reg] / S.denL[il];
        v = v > 0.f ? v : expm1f(v);
        int n = (ct << 8) | (i >> 3);
        int f = ((i & 7) << 6) | nloc;
        out[((size_t)b*NN + n)*FOUT + f] = v;
      }
    }
  }
}

// ---------------------------------------------------------------------------
extern "C" void kernel_launch(void* const* d_in, const int* in_sizes, int n_in,
                              void* d_out, int out_size, void* d_ws, size_t ws_size,
                              hipStream_t stream)
{
  const float* hin = (const float*)d_in[0];   // h   f32 [4,2048,512]
  const int*   adj = (const int*)d_in[1];     // adj int32 [4,2048,2048]
  // d_in[2] = W_l : mathematically dead (softmax(el[i]+er[j]) == softmax(er[j]))
  const float* Wr  = (const float*)d_in[3];   // W_r f32 [512,512]
  const float* av  = (const float*)d_in[4];   // a   f32 [64,1]
  float* out = (float*)d_out;

  // Workspace overlays (peak ~34.9 MB):
  //   [0, 8.39M)      hHi   -> dead after phase1; overlaid by Vt
  //   [8.39M,16.78M)  hLo   -> dead after phase1
  //   [16.78M,17.30M) wTh   -> dead after phase1
  //   [17.30M,17.83M) wTl   -> dead after phase1
  //   [17.83M,34.60M) Whr (f32)
  //   [34.60M,34.86M) er
  //   [34.86M,+8B)    barrier counters (zeroed each call)
  //   [0, 8.52M)      Vt (bf16, 520 rows/batch) after phase1
  char* ws = (char*)d_ws;
  unsigned short* hHi = (unsigned short*)(ws);
  unsigned short* hLo = (unsigned short*)(ws + 8388608);
  unsigned short* wTh = (unsigned short*)(ws + 16777216);
  unsigned short* wTl = (unsigned short*)(ws + 17301504);
  float* Whr  = (float*)(ws + 17825792);
  float* er   = (float*)(ws + 34603008);
  unsigned short* Vt = (unsigned short*)(ws);
  unsigned* bar = (unsigned*)(ws + 34865152);

  hipMemsetAsync(bar, 0, 8, stream);
  k_fused<<<dim3(NBLK), dim3(256), 0, stream>>>(
      hin, adj, Wr, av, out, hHi, hLo, wTh, wTl, Whr, er, Vt, bar);
}

// Round 10
// 202.749 us; speedup vs baseline: 2.1200x; 1.8339x over previous
//
#include <hip/hip_runtime.h>

// Problem constants (B,N,F_in,F_out fixed by setup_inputs)
#define NB   4
#define NN   2048
#define FIN  512
#define FOUT 512
#define NHD  8
#define DH   64
#define VTR  520   // Vt rows per batch: 512 data (8 heads x 64 d) + 8 denominator
#define SLOPE 0.2f

typedef __attribute__((ext_vector_type(8)))  short bhalf8;
typedef __attribute__((ext_vector_type(16))) float f32x16;

__device__ __forceinline__ void load_lds16(const void* g, void* l) {
  __builtin_amdgcn_global_load_lds(
      (const __attribute__((address_space(1))) unsigned int*)g,
      (__attribute__((address_space(3))) unsigned int*)l, 16, 0, 0);
}

// RNE float->bf16 (finite values only in this pipeline)
__device__ __forceinline__ unsigned short bfrne(float x) {
  unsigned int u = __float_as_uint(x);
  return (unsigned short)((u + 0x7FFFu + ((u >> 16) & 1u)) >> 16);
}
__device__ __forceinline__ float bf2f(unsigned short u) {
  return __uint_as_float(((unsigned int)u) << 16);
}

// split x,y into bf16 hi (RNE) + bf16 lo (RNE of residual); returns packed pairs
__device__ __forceinline__ void split2(float x, float y,
                                       unsigned int& hp, unsigned int& lp) {
  unsigned int ux = __float_as_uint(x), uy = __float_as_uint(y);
  unsigned int rx = (ux + 0x7FFFu + ((ux >> 16) & 1u)) & 0xFFFF0000u;
  unsigned int ry = (uy + 0x7FFFu + ((uy >> 16) & 1u)) & 0xFFFF0000u;
  float lx = x - __uint_as_float(rx);
  float ly = y - __uint_as_float(ry);
  unsigned int vx = __float_as_uint(lx), vy = __float_as_uint(ly);
  hp = (rx >> 16) | ry;
  lp = ((vx + 0x7FFFu + ((vx >> 16) & 1u)) >> 16)
     | ((vy + 0x7FFFu + ((vy >> 16) & 1u)) & 0xFFFF0000u);
}

// ---------------------------------------------------------------------------
// P: blocks [0,2048): h -> hHi/hLo split; [2048,2112): Wr transpose+split.
// ---------------------------------------------------------------------------
__global__ __launch_bounds__(256) void k_split_prep(
    const float* __restrict__ h,
    unsigned short* __restrict__ hHi, unsigned short* __restrict__ hLo,
    const float* __restrict__ Wr,
    unsigned short* __restrict__ wTh, unsigned short* __restrict__ wTl)
{
  __shared__ float s[64][65];
  const int t = threadIdx.x;
  if (blockIdx.x < 2048) {
    size_t base = ((size_t)blockIdx.x * 256 + t) * 8;
    float4 a = *(const float4*)(h + base);
    float4 b = *(const float4*)(h + base + 4);
    uint4 uh, ul;
    split2(a.x, a.y, uh.x, ul.x);
    split2(a.z, a.w, uh.y, ul.y);
    split2(b.x, b.y, uh.z, ul.z);
    split2(b.z, b.w, uh.w, ul.w);
    *(uint4*)(hHi + base) = uh;
    *(uint4*)(hLo + base) = ul;
    return;
  }
  const int bid2 = blockIdx.x - 2048;
  const int n0 = (bid2 & 7) * 64, k0 = (bid2 >> 3) * 64;
#pragma unroll
  for (int p = 0; p < 4; ++p) {
    int row = p * 16 + (t >> 4);       // k-local
    int col = (t & 15) * 4;            // n-local
    float4 v = *(const float4*)(Wr + (size_t)(k0 + row) * FOUT + n0 + col);
    s[row][col] = v.x; s[row][col+1] = v.y; s[row][col+2] = v.z; s[row][col+3] = v.w;
  }
  __syncthreads();
  const int n = t >> 2;           // 0..63
  const int ks = (t & 3) * 16;    // 0,16,32,48
  uint4 h0, h1, l0, l1;
  split2(s[ks+ 0][n], s[ks+ 1][n], h0.x, l0.x);
  split2(s[ks+ 2][n], s[ks+ 3][n], h0.y, l0.y);
  split2(s[ks+ 4][n], s[ks+ 5][n], h0.z, l0.z);
  split2(s[ks+ 6][n], s[ks+ 7][n], h0.w, l0.w);
  split2(s[ks+ 8][n], s[ks+ 9][n], h1.x, l1.x);
  split2(s[ks+10][n], s[ks+11][n], h1.y, l1.y);
  split2(s[ks+12][n], s[ks+13][n], h1.z, l1.z);
  split2(s[ks+14][n], s[ks+15][n], h1.w, l1.w);
  size_t o = (size_t)(n0 + n) * FIN + k0 + ks;
  *(uint4*)(wTh + o) = h0; *(uint4*)(wTh + o + 8) = h1;
  *(uint4*)(wTl + o) = l0; *(uint4*)(wTl + o + 8) = l1;
}

// ---------------------------------------------------------------------------
// K1: Whr(bf16) = leaky_relu(h @ Wr) split-bf16 MFMA; er via shuffle+LDS
//     combine -> plain store. Whr stored bf16 (halves downstream traffic;
//     Vt is re-rounded to bf16 anyway, double-rounding ~0.4% rel).
// ---------------------------------------------------------------------------
__global__ __launch_bounds__(256) void k_gemm_whr_mfma(
    const unsigned short* __restrict__ hHi, const unsigned short* __restrict__ hLo,
    const unsigned short* __restrict__ wTh, const unsigned short* __restrict__ wTl,
    unsigned short* __restrict__ Whr, const float* __restrict__ av,
    float* __restrict__ er)
{
  __shared__ unsigned short sAh[128*64], sAl[128*64];
  __shared__ unsigned short sBh[64*64],  sBl[64*64];
  __shared__ float erT[128][2];
  const int tid = threadIdx.x, lane = tid & 63, wv = tid >> 6;
  const int Bid = blockIdx.x;
  const int g8 = Bid & 7, idx = Bid >> 3;     // XCD-grouped
  const int sg = idx >> 3, ct = idx & 7;      // col tiles sweep fastest
  const int c0 = ct * 64;
  const int row0 = (g8 * 8 + sg) * 128;

  const unsigned short* pAh[4]; const unsigned short* pAl[4];
  unsigned short *dAh[4], *dAl[4];
#pragma unroll
  for (int t = 0; t < 4; ++t) {
    int I  = wv + t * 4;
    int rl = I * 8 + (lane >> 3);
    int gk = (lane & 7) ^ (rl & 7);
    pAh[t] = hHi + (size_t)(row0 + rl) * FIN + gk * 8;
    pAl[t] = hLo + (size_t)(row0 + rl) * FIN + gk * 8;
    dAh[t] = sAh + I * 512;  dAl[t] = sAl + I * 512;
  }
  const unsigned short* pBh[2]; const unsigned short* pBl[2];
  unsigned short *dBh[2], *dBl[2];
#pragma unroll
  for (int t = 0; t < 2; ++t) {
    int I  = wv + t * 4;
    int rl = I * 8 + (lane >> 3);
    int gk = (lane & 7) ^ (rl & 7);
    pBh[t] = wTh + (size_t)(c0 + rl) * FIN + gk * 8;
    pBl[t] = wTl + (size_t)(c0 + rl) * FIN + gk * 8;
    dBh[t] = sBh + I * 512;  dBl[t] = sBl + I * 512;
  }

  const int wi = wv >> 1, wc = wv & 1;
  const int l31 = lane & 31, half = lane >> 5;
  const int aoff0 = (wi*64 +      l31) * 64;
  const int aoff1 = (wi*64 + 32 + l31) * 64;
  const int boff  = (wc*32 +      l31) * 64;
  f32x16 acc0 = {}; f32x16 acc1 = {};

  for (int k0 = 0; k0 < FIN; k0 += 64) {
#pragma unroll
    for (int t = 0; t < 4; ++t) { load_lds16(pAh[t] + k0, dAh[t]);
                                  load_lds16(pAl[t] + k0, dAl[t]); }
#pragma unroll
    for (int t = 0; t < 2; ++t) { load_lds16(pBh[t] + k0, dBh[t]);
                                  load_lds16(pBl[t] + k0, dBl[t]); }
    __syncthreads();
#pragma unroll
    for (int kb = 0; kb < 4; ++kb) {
      int kg = ((kb*2 + half) ^ (lane & 7)) * 8;
      bhalf8 bh  = *(const bhalf8*)&sBh[boff  + kg];
      bhalf8 bl  = *(const bhalf8*)&sBl[boff  + kg];
      bhalf8 a0h = *(const bhalf8*)&sAh[aoff0 + kg];
      bhalf8 a0l = *(const bhalf8*)&sAl[aoff0 + kg];
      bhalf8 a1h = *(const bhalf8*)&sAh[aoff1 + kg];
      bhalf8 a1l = *(const bhalf8*)&sAl[aoff1 + kg];
      acc0 = __builtin_amdgcn_mfma_f32_32x32x16_bf16(a0h, bh, acc0, 0, 0, 0);
      acc1 = __builtin_amdgcn_mfma_f32_32x32x16_bf16(a1h, bh, acc1, 0, 0, 0);
      acc0 = __builtin_amdgcn_mfma_f32_32x32x16_bf16(a0l, bh, acc0, 0, 0, 0);
      acc1 = __builtin_amdgcn_mfma_f32_32x32x16_bf16(a1l, bh, acc1, 0, 0, 0);
      acc0 = __builtin_amdgcn_mfma_f32_32x32x16_bf16(a0h, bl, acc0, 0, 0, 0);
      acc1 = __builtin_amdgcn_mfma_f32_32x32x16_bf16(a1h, bl, acc1, 0, 0, 0);
    }
    __syncthreads();
  }

  // epilogue: leaky_relu + remap store (bf16) + er partial (dd = wc*32+l31)
  const float a_d = av[wc*32 + l31];
#pragma unroll
  for (int mi = 0; mi < 2; ++mi) {
    const f32x16 a = mi ? acc1 : acc0;
#pragma unroll
    for (int reg = 0; reg < 16; ++reg) {
      int rmap = (reg & 3) + 8*(reg >> 2) + 4*half;
      int rowloc = wi*64 + mi*32 + rmap;
      int grow = row0 + rowloc;
      int b  = grow >> 11;
      int n  = grow & 2047;
      int hd = n >> 8;
      int jj = ((n & 255) << 3) | ct;
      float v = a[reg];
      v = v > 0.f ? v : SLOPE * v;
      Whr[(((size_t)(b*NHD + hd)) * NN + jj) * DH + (wc*32 + l31)] = bfrne(v);
      float p = v * a_d;
      p += __shfl_xor(p, 16, 32);
      p += __shfl_xor(p,  8, 32);
      p += __shfl_xor(p,  4, 32);
      p += __shfl_xor(p,  2, 32);
      p += __shfl_xor(p,  1, 32);
      if (l31 == 0) erT[rowloc][wc] = p;
    }
  }
  __syncthreads();
  if (tid < 128) {
    int grow = row0 + tid;
    int b  = grow >> 11;
    int n  = grow & 2047;
    int hd = n >> 8;
    int jj = ((n & 255) << 3) | ct;
    er[((size_t)(b*NHD + hd)) * NN + jj] = erT[tid][0] + erT[tid][1];
  }
}

// ---------------------------------------------------------------------------
// K2: fused softmax + Vt build. Grid (jc=8, h=8, b=4). Whr now bf16.
// ---------------------------------------------------------------------------
__global__ __launch_bounds__(256) void k_softvt(
    const unsigned short* __restrict__ Whr, const float* __restrict__ er,
    unsigned short* __restrict__ Vt)
{
  __shared__ float wm[4];
  __shared__ float wbuf[256];
  __shared__ unsigned short tile[64][264];   // [d][j-local], padded
  const int tid = threadIdx.x;
  const int jc = blockIdx.x, hh = blockIdx.y, b = blockIdx.z;
  const float* ep = er + ((size_t)(b*NHD + hh)) * NN;
  float m = -1e30f;
  for (int j = tid; j < NN; j += 256) m = fmaxf(m, ep[j]);
#pragma unroll
  for (int off = 32; off; off >>= 1) m = fmaxf(m, __shfl_down(m, off, 64));
  if ((tid & 63) == 0) wm[tid >> 6] = m;
  __syncthreads();
  const float mm = fmaxf(fmaxf(wm[0], wm[1]), fmaxf(wm[2], wm[3]));
  const int j0 = jc * 256;
  float w = expf(ep[j0 + tid] - mm);
  wbuf[tid] = w;
  Vt[((size_t)(b*VTR + 512 + hh)) * NN + j0 + tid] = bfrne(w);
  __syncthreads();
  const size_t wbase = ((size_t)(b*NHD + hh)) * NN;
#pragma unroll
  for (int p = 0; p < 16; ++p) {
    int jr = p*16 + (tid >> 4);
    int dc = (tid & 15) * 4;
    ushort4 v = *(const ushort4*)(Whr + (wbase + j0 + jr) * DH + dc);
    float wj = wbuf[jr];
    tile[dc+0][jr] = bfrne(bf2f(v.x) * wj);
    tile[dc+1][jr] = bfrne(bf2f(v.y) * wj);
    tile[dc+2][jr] = bfrne(bf2f(v.z) * wj);
    tile[dc+3][jr] = bfrne(bf2f(v.w) * wj);
  }
  __syncthreads();
#pragma unroll
  for (int q = 0; q < 8; ++q) {
    int idx = q*256 + tid;
    int d = idx >> 5, seg = idx & 31;
    uint4 t16 = *(const uint4*)&tile[d][seg*8];
    *(uint4*)(Vt + ((size_t)(b*VTR + hh*64 + d)) * NN + j0 + seg*8) = t16;
  }
}

// ---------------------------------------------------------------------------
// K3: attention matmul + epilogue, BM=64 for 4 blocks/CU (latency hiding).
//   Grid 1024 = 8 XCD-groups x 8 ct x 16 row-stripes; all 128 blocks of an
//   XCD co-resident -> adj stripe fetched once into L2, shared by 8 ct-blocks.
//   Waves 2x2, wave tile 32x32. den MFMA only on wc==0 waves (reuses a-frag).
//   sB double-buffered; adj prefetched into regs one iteration ahead.
// ---------------------------------------------------------------------------
__global__ __launch_bounds__(256, 4) void k_attn_out(
    const int* __restrict__ adj, const unsigned short* __restrict__ Vt,
    float* __restrict__ out)
{
  __shared__ unsigned short sA[64][72];      // [i][k], +8 pad
  __shared__ unsigned short sB[2][72*64];    // dbuf: rows 0..63 data, 64..71 den
  __shared__ float denL[64];
  const int tid = threadIdx.x;
  const int lane = tid & 63, wv = tid >> 6;
  const int Bid = blockIdx.x;
  const int g8 = Bid & 7, rest = Bid >> 3;
  const int ct = rest & 7, sg = rest >> 3;     // ct 0..7, sg 0..15
  const int row0 = (g8*16 + sg) * 64;          // flat row in [0,8192)
  const int b = row0 >> 11;

  const unsigned short* pB[3];
  int dOff[3];
#pragma unroll
  for (int t = 0; t < 2; ++t) {
    int I  = wv + t*4;
    int rl = I*8 + (lane >> 3);
    int gk = (lane & 7) ^ (rl & 7);
    pB[t] = Vt + ((size_t)(b*VTR + ct*64 + rl))*NN + gk*8;
    dOff[t] = I*512;
  }
  {
    int x  = lane >> 3;
    int gk = (lane & 7) ^ (x & 7);
    pB[2] = Vt + ((size_t)(b*VTR + 512 + x))*NN + gk*8;
    dOff[2] = 64*64;
  }

  const int* adjp = adj + (size_t)b*NN*NN + (size_t)(row0 & 2047)*NN
                    + (tid >> 3)*NN + (tid & 7)*8;
  unsigned short* sAp = &sA[tid >> 3][(tid & 7)*8];

  const int wi = wv >> 1, wc = wv & 1;
  const int l31 = lane & 31, half = lane >> 5;
  f32x16 acc0 = {}; f32x16 acc2 = {};
  const unsigned short* aRd = &sA[wi*32 + l31][half*8];
  const int nloc = wc*32 + l31;

  // prologue: DMA B(0) into buf0, adj(0) into regs
  load_lds16(pB[0], &sB[0][dOff[0]]);
  load_lds16(pB[1], &sB[0][dOff[1]]);
  if (wv == 0) load_lds16(pB[2], &sB[0][dOff[2]]);
  int4 q[4];
#pragma unroll
  for (int rr = 0; rr < 2; ++rr) {
    q[2*rr]   = *(const int4*)(adjp + rr*32*NN);
    q[2*rr+1] = *(const int4*)(adjp + rr*32*NN + 4);
  }

  for (int it = 0; it < 32; ++it) {
    const int cur = it & 1;
#pragma unroll
    for (int rr = 0; rr < 2; ++rr) {
      uint4 u;
      u.x = (unsigned)(q[2*rr].x   | (q[2*rr].y   << 16)) * 0x3F80u;
      u.y = (unsigned)(q[2*rr].z   | (q[2*rr].w   << 16)) * 0x3F80u;
      u.z = (unsigned)(q[2*rr+1].x | (q[2*rr+1].y << 16)) * 0x3F80u;
      u.w = (unsigned)(q[2*rr+1].z | (q[2*rr+1].w << 16)) * 0x3F80u;
      *(uint4*)(sAp + rr*32*72) = u;
    }
    __syncthreads();
    if (it < 31) {
      const int nk = (it + 1) * 64;
      unsigned short* nb = sB[cur ^ 1];
      load_lds16(pB[0] + nk, nb + dOff[0]);
      load_lds16(pB[1] + nk, nb + dOff[1]);
      if (wv == 0) load_lds16(pB[2] + nk, nb + dOff[2]);
#pragma unroll
      for (int rr = 0; rr < 2; ++rr) {
        q[2*rr]   = *(const int4*)(adjp + rr*32*NN + nk);
        q[2*rr+1] = *(const int4*)(adjp + rr*32*NN + nk + 4);
      }
    }
    const unsigned short* sBc = sB[cur];
#pragma unroll
    for (int kb = 0; kb < 4; ++kb) {
      int kg = (kb*2 + half) ^ (lane & 7);
      bhalf8 bf = *(const bhalf8*)&sBc[nloc*64 + kg*8];
      bhalf8 a  = *(const bhalf8*)(aRd + kb*16);
      acc0 = __builtin_amdgcn_mfma_f32_32x32x16_bf16(a, bf, acc0, 0, 0, 0);
      if (wc == 0) {
        bhalf8 bf2 = {};
        if (l31 < 8) bf2 = *(const bhalf8*)&sBc[(64 + l31)*64 + kg*8];
        acc2 = __builtin_amdgcn_mfma_f32_32x32x16_bf16(a, bf2, acc2, 0, 0, 0);
      }
    }
    __syncthreads();
  }
  // den extraction: acc2 (wc==0 waves) rows = wi*32 + rmap; den col == ct
  if (wc == 0 && l31 == ct) {
#pragma unroll
    for (int reg = 0; reg < 16; ++reg)
      denL[wi*32 + (reg & 3) + 8*(reg >> 2) + 4*half] = acc2[reg];
  }
  __syncthreads();
  // fused div + elu + raw-reshape remap store
  const int ib = row0 & 2047;
#pragma unroll
  for (int reg = 0; reg < 16; ++reg) {
    int il = wi*32 + (reg & 3) + 8*(reg >> 2) + 4*half;
    int i  = ib + il;
    float v = acc0[reg] / denL[il];
    v = v > 0.f ? v : expm1f(v);
    int n = (ct << 8) | (i >> 3);
    int f = ((i & 7) << 6) | nloc;
    out[((size_t)b*NN + n)*FOUT + f] = v;
  }
}

// ---------------------------------------------------------------------------
extern "C" void kernel_launch(void* const* d_in, const int* in_sizes, int n_in,
                              void* d_out, int out_size, void* d_ws, size_t ws_size,
                              hipStream_t stream)
{
  const float* hin = (const float*)d_in[0];   // h   f32 [4,2048,512]
  const int*   adj = (const int*)d_in[1];     // adj int32 [4,2048,2048]
  // d_in[2] = W_l : mathematically dead (softmax(el[i]+er[j]) == softmax(er[j]))
  const float* Wr  = (const float*)d_in[3];   // W_r f32 [512,512]
  const float* av  = (const float*)d_in[4];   // a   f32 [64,1]
  float* out = (float*)d_out;

  // Workspace overlays (peak ~34.9 MB):
  //   [0, 8.39M)      hHi   -> dead after gemm; overlaid by Vt
  //   [8.39M,16.78M)  hLo   -> dead after gemm
  //   [16.78M,17.30M) wTh   -> dead after gemm
  //   [17.30M,17.83M) wTl   -> dead after gemm
  //   [17.83M,26.2M)  Whr (bf16)
  //   [34.60M,34.86M) er
  //   [0, 8.52M)      Vt (bf16, 520 rows/batch) after gemm
  char* ws = (char*)d_ws;
  unsigned short* hHi = (unsigned short*)(ws);
  unsigned short* hLo = (unsigned short*)(ws + 8388608);
  unsigned short* wTh = (unsigned short*)(ws + 16777216);
  unsigned short* wTl = (unsigned short*)(ws + 17301504);
  unsigned short* Whr = (unsigned short*)(ws + 17825792);
  float* er   = (float*)(ws + 34603008);
  unsigned short* Vt = (unsigned short*)(ws);

  k_split_prep   <<<dim3(2112),    256, 0, stream>>>(hin, hHi, hLo, Wr, wTh, wTl);
  k_gemm_whr_mfma<<<dim3(512),     256, 0, stream>>>(hHi, hLo, wTh, wTl, Whr, av, er);
  k_softvt       <<<dim3(8, 8, 4), 256, 0, stream>>>(Whr, er, Vt);
  k_attn_out     <<<dim3(1024),    256, 0, stream>>>(adj, Vt, out);
}

// Round 11
// 198.585 us; speedup vs baseline: 2.1645x; 1.0210x over previous
//
#include <hip/hip_runtime.h>

// Problem constants (B,N,F_in,F_out fixed by setup_inputs)
#define NB   4
#define NN   2048
#define FIN  512
#define FOUT 512
#define NHD  8
#define DH   64
#define VTR  520   // Vt rows per batch: 512 data (8 heads x 64 d) + 8 denominator
#define SLOPE 0.2f

typedef __attribute__((ext_vector_type(8)))  short bhalf8;
typedef __attribute__((ext_vector_type(16))) float f32x16;

__device__ __forceinline__ void load_lds16(const void* g, void* l) {
  __builtin_amdgcn_global_load_lds(
      (const __attribute__((address_space(1))) unsigned int*)g,
      (__attribute__((address_space(3))) unsigned int*)l, 16, 0, 0);
}

// RNE float->bf16 (finite values only in this pipeline)
__device__ __forceinline__ unsigned short bfrne(float x) {
  unsigned int u = __float_as_uint(x);
  return (unsigned short)((u + 0x7FFFu + ((u >> 16) & 1u)) >> 16);
}
__device__ __forceinline__ float bf2f(unsigned short u) {
  return __uint_as_float(((unsigned int)u) << 16);
}

// split x,y into bf16 hi (RNE) + bf16 lo (RNE of residual); returns packed pairs
__device__ __forceinline__ void split2(float x, float y,
                                       unsigned int& hp, unsigned int& lp) {
  unsigned int ux = __float_as_uint(x), uy = __float_as_uint(y);
  unsigned int rx = (ux + 0x7FFFu + ((ux >> 16) & 1u)) & 0xFFFF0000u;
  unsigned int ry = (uy + 0x7FFFu + ((uy >> 16) & 1u)) & 0xFFFF0000u;
  float lx = x - __uint_as_float(rx);
  float ly = y - __uint_as_float(ry);
  unsigned int vx = __float_as_uint(lx), vy = __float_as_uint(ly);
  hp = (rx >> 16) | ry;
  lp = ((vx + 0x7FFFu + ((vx >> 16) & 1u)) >> 16)
     | ((vy + 0x7FFFu + ((vy >> 16) & 1u)) & 0xFFFF0000u);
}

// ---------------------------------------------------------------------------
// P: blocks [0,2048): h -> hHi/hLo split; [2048,2112): Wr transpose+split.
// ---------------------------------------------------------------------------
__global__ __launch_bounds__(256) void k_split_prep(
    const float* __restrict__ h,
    unsigned short* __restrict__ hHi, unsigned short* __restrict__ hLo,
    const float* __restrict__ Wr,
    unsigned short* __restrict__ wTh, unsigned short* __restrict__ wTl)
{
  __shared__ float s[64][65];
  const int t = threadIdx.x;
  if (blockIdx.x < 2048) {
    size_t base = ((size_t)blockIdx.x * 256 + t) * 8;
    float4 a = *(const float4*)(h + base);
    float4 b = *(const float4*)(h + base + 4);
    uint4 uh, ul;
    split2(a.x, a.y, uh.x, ul.x);
    split2(a.z, a.w, uh.y, ul.y);
    split2(b.x, b.y, uh.z, ul.z);
    split2(b.z, b.w, uh.w, ul.w);
    *(uint4*)(hHi + base) = uh;
    *(uint4*)(hLo + base) = ul;
    return;
  }
  const int bid2 = blockIdx.x - 2048;
  const int n0 = (bid2 & 7) * 64, k0 = (bid2 >> 3) * 64;
#pragma unroll
  for (int p = 0; p < 4; ++p) {
    int row = p * 16 + (t >> 4);       // k-local
    int col = (t & 15) * 4;            // n-local
    float4 v = *(const float4*)(Wr + (size_t)(k0 + row) * FOUT + n0 + col);
    s[row][col] = v.x; s[row][col+1] = v.y; s[row][col+2] = v.z; s[row][col+3] = v.w;
  }
  __syncthreads();
  const int n = t >> 2;           // 0..63
  const int ks = (t & 3) * 16;    // 0,16,32,48
  uint4 h0, h1, l0, l1;
  split2(s[ks+ 0][n], s[ks+ 1][n], h0.x, l0.x);
  split2(s[ks+ 2][n], s[ks+ 3][n], h0.y, l0.y);
  split2(s[ks+ 4][n], s[ks+ 5][n], h0.z, l0.z);
  split2(s[ks+ 6][n], s[ks+ 7][n], h0.w, l0.w);
  split2(s[ks+ 8][n], s[ks+ 9][n], h1.x, l1.x);
  split2(s[ks+10][n], s[ks+11][n], h1.y, l1.y);
  split2(s[ks+12][n], s[ks+13][n], h1.z, l1.z);
  split2(s[ks+14][n], s[ks+15][n], h1.w, l1.w);
  size_t o = (size_t)(n0 + n) * FIN + k0 + ks;
  *(uint4*)(wTh + o) = h0; *(uint4*)(wTh + o + 8) = h1;
  *(uint4*)(wTl + o) = l0; *(uint4*)(wTl + o + 8) = l1;
}

// ---------------------------------------------------------------------------
// K1: Whr(bf16) = leaky_relu(h @ Wr) split-bf16 MFMA; er via shuffle+LDS
//     combine -> plain store.
// ---------------------------------------------------------------------------
__global__ __launch_bounds__(256) void k_gemm_whr_mfma(
    const unsigned short* __restrict__ hHi, const unsigned short* __restrict__ hLo,
    const unsigned short* __restrict__ wTh, const unsigned short* __restrict__ wTl,
    unsigned short* __restrict__ Whr, const float* __restrict__ av,
    float* __restrict__ er)
{
  __shared__ unsigned short sAh[128*64], sAl[128*64];
  __shared__ unsigned short sBh[64*64],  sBl[64*64];
  __shared__ float erT[128][2];
  const int tid = threadIdx.x, lane = tid & 63, wv = tid >> 6;
  const int Bid = blockIdx.x;
  const int g8 = Bid & 7, idx = Bid >> 3;     // XCD-grouped
  const int sg = idx >> 3, ct = idx & 7;      // col tiles sweep fastest
  const int c0 = ct * 64;
  const int row0 = (g8 * 8 + sg) * 128;

  const unsigned short* pAh[4]; const unsigned short* pAl[4];
  unsigned short *dAh[4], *dAl[4];
#pragma unroll
  for (int t = 0; t < 4; ++t) {
    int I  = wv + t * 4;
    int rl = I * 8 + (lane >> 3);
    int gk = (lane & 7) ^ (rl & 7);
    pAh[t] = hHi + (size_t)(row0 + rl) * FIN + gk * 8;
    pAl[t] = hLo + (size_t)(row0 + rl) * FIN + gk * 8;
    dAh[t] = sAh + I * 512;  dAl[t] = sAl + I * 512;
  }
  const unsigned short* pBh[2]; const unsigned short* pBl[2];
  unsigned short *dBh[2], *dBl[2];
#pragma unroll
  for (int t = 0; t < 2; ++t) {
    int I  = wv + t * 4;
    int rl = I * 8 + (lane >> 3);
    int gk = (lane & 7) ^ (rl & 7);
    pBh[t] = wTh + (size_t)(c0 + rl) * FIN + gk * 8;
    pBl[t] = wTl + (size_t)(c0 + rl) * FIN + gk * 8;
    dBh[t] = sBh + I * 512;  dBl[t] = sBl + I * 512;
  }

  const int wi = wv >> 1, wc = wv & 1;
  const int l31 = lane & 31, half = lane >> 5;
  const int aoff0 = (wi*64 +      l31) * 64;
  const int aoff1 = (wi*64 + 32 + l31) * 64;
  const int boff  = (wc*32 +      l31) * 64;
  f32x16 acc0 = {}; f32x16 acc1 = {};

  for (int k0 = 0; k0 < FIN; k0 += 64) {
#pragma unroll
    for (int t = 0; t < 4; ++t) { load_lds16(pAh[t] + k0, dAh[t]);
                                  load_lds16(pAl[t] + k0, dAl[t]); }
#pragma unroll
    for (int t = 0; t < 2; ++t) { load_lds16(pBh[t] + k0, dBh[t]);
                                  load_lds16(pBl[t] + k0, dBl[t]); }
    __syncthreads();
#pragma unroll
    for (int kb = 0; kb < 4; ++kb) {
      int kg = ((kb*2 + half) ^ (lane & 7)) * 8;
      bhalf8 bh  = *(const bhalf8*)&sBh[boff  + kg];
      bhalf8 bl  = *(const bhalf8*)&sBl[boff  + kg];
      bhalf8 a0h = *(const bhalf8*)&sAh[aoff0 + kg];
      bhalf8 a0l = *(const bhalf8*)&sAl[aoff0 + kg];
      bhalf8 a1h = *(const bhalf8*)&sAh[aoff1 + kg];
      bhalf8 a1l = *(const bhalf8*)&sAl[aoff1 + kg];
      acc0 = __builtin_amdgcn_mfma_f32_32x32x16_bf16(a0h, bh, acc0, 0, 0, 0);
      acc1 = __builtin_amdgcn_mfma_f32_32x32x16_bf16(a1h, bh, acc1, 0, 0, 0);
      acc0 = __builtin_amdgcn_mfma_f32_32x32x16_bf16(a0l, bh, acc0, 0, 0, 0);
      acc1 = __builtin_amdgcn_mfma_f32_32x32x16_bf16(a1l, bh, acc1, 0, 0, 0);
      acc0 = __builtin_amdgcn_mfma_f32_32x32x16_bf16(a0h, bl, acc0, 0, 0, 0);
      acc1 = __builtin_amdgcn_mfma_f32_32x32x16_bf16(a1h, bl, acc1, 0, 0, 0);
    }
    __syncthreads();
  }

  // epilogue: leaky_relu + remap store (bf16) + er partial (dd = wc*32+l31)
  const float a_d = av[wc*32 + l31];
#pragma unroll
  for (int mi = 0; mi < 2; ++mi) {
    const f32x16 a = mi ? acc1 : acc0;
#pragma unroll
    for (int reg = 0; reg < 16; ++reg) {
      int rmap = (reg & 3) + 8*(reg >> 2) + 4*half;
      int rowloc = wi*64 + mi*32 + rmap;
      int grow = row0 + rowloc;
      int b  = grow >> 11;
      int n  = grow & 2047;
      int hd = n >> 8;
      int jj = ((n & 255) << 3) | ct;
      float v = a[reg];
      v = v > 0.f ? v : SLOPE * v;
      Whr[(((size_t)(b*NHD + hd)) * NN + jj) * DH + (wc*32 + l31)] = bfrne(v);
      float p = v * a_d;
      p += __shfl_xor(p, 16, 32);
      p += __shfl_xor(p,  8, 32);
      p += __shfl_xor(p,  4, 32);
      p += __shfl_xor(p,  2, 32);
      p += __shfl_xor(p,  1, 32);
      if (l31 == 0) erT[rowloc][wc] = p;
    }
  }
  __syncthreads();
  if (tid < 128) {
    int grow = row0 + tid;
    int b  = grow >> 11;
    int n  = grow & 2047;
    int hd = n >> 8;
    int jj = ((n & 255) << 3) | ct;
    er[((size_t)(b*NHD + hd)) * NN + jj] = erT[tid][0] + erT[tid][1];
  }
}

// ---------------------------------------------------------------------------
// K2: fused softmax + Vt build. Grid (jc=8, h=8, b=4). Whr bf16.
// ---------------------------------------------------------------------------
__global__ __launch_bounds__(256) void k_softvt(
    const unsigned short* __restrict__ Whr, const float* __restrict__ er,
    unsigned short* __restrict__ Vt)
{
  __shared__ float wm[4];
  __shared__ float wbuf[256];
  __shared__ unsigned short tile[64][264];   // [d][j-local], padded
  const int tid = threadIdx.x;
  const int jc = blockIdx.x, hh = blockIdx.y, b = blockIdx.z;
  const float* ep = er + ((size_t)(b*NHD + hh)) * NN;
  float m = -1e30f;
  for (int j = tid; j < NN; j += 256) m = fmaxf(m, ep[j]);
#pragma unroll
  for (int off = 32; off; off >>= 1) m = fmaxf(m, __shfl_down(m, off, 64));
  if ((tid & 63) == 0) wm[tid >> 6] = m;
  __syncthreads();
  const float mm = fmaxf(fmaxf(wm[0], wm[1]), fmaxf(wm[2], wm[3]));
  const int j0 = jc * 256;
  float w = expf(ep[j0 + tid] - mm);
  wbuf[tid] = w;
  Vt[((size_t)(b*VTR + 512 + hh)) * NN + j0 + tid] = bfrne(w);
  __syncthreads();
  const size_t wbase = ((size_t)(b*NHD + hh)) * NN;
#pragma unroll
  for (int p = 0; p < 16; ++p) {
    int jr = p*16 + (tid >> 4);
    int dc = (tid & 15) * 4;
    ushort4 v = *(const ushort4*)(Whr + (wbase + j0 + jr) * DH + dc);
    float wj = wbuf[jr];
    tile[dc+0][jr] = bfrne(bf2f(v.x) * wj);
    tile[dc+1][jr] = bfrne(bf2f(v.y) * wj);
    tile[dc+2][jr] = bfrne(bf2f(v.z) * wj);
    tile[dc+3][jr] = bfrne(bf2f(v.w) * wj);
  }
  __syncthreads();
#pragma unroll
  for (int q = 0; q < 8; ++q) {
    int idx = q*256 + tid;
    int d = idx >> 5, seg = idx & 31;
    uint4 t16 = *(const uint4*)&tile[d][seg*8];
    *(uint4*)(Vt + ((size_t)(b*VTR + hh*64 + d)) * NN + j0 + seg*8) = t16;
  }
}

// ---------------------------------------------------------------------------
// K3: attention matmul + epilogue. L3-traffic-minimizing shape:
//   512-thread blocks (8 waves, 2 row x 4 col), BM=128, BN=136 (128 data
//   cols of quarter ctq + all 8 den rows). Grid 256 = 8 XCDs x (4 ctq x 8 sg):
//   the 4 ctq blocks of one row-stripe are co-resident on one XCD -> the
//   1 MB adj stripe is fetched from L3 ONCE per XCD (67 MB total vs 537 MB
//   at BN=64) and re-served from L2. B tiles shared by 8 sg-blocks in-XCD.
//   den MFMA on wc<2 waves (a0/a1 reuse covers all 128 rows); epilogue
//   divides by the pass's 2 heads, applies elu + raw-reshape remap.
// ---------------------------------------------------------------------------
__global__ __launch_bounds__(512, 1) void k_attn_out(
    const int* __restrict__ adj, const unsigned short* __restrict__ Vt,
    float* __restrict__ out)
{
  __shared__ unsigned short sA[128][72];   // [i][k], +8 pad
  __shared__ unsigned short sB[136*64];    // rows 0..127 data, 128..135 den
  __shared__ float denL[128][2];
  const int tid = threadIdx.x;
  const int lane = tid & 63, wv = tid >> 6;      // wv 0..7
  const int Bid = blockIdx.x;
  const int g8 = Bid & 7, idx = Bid >> 3;        // 0..31
  const int ctq = idx & 3, sg = idx >> 2;        // ctq 0..3 fastest (co-resident)
  const int row0 = (g8*8 + sg) * 128;            // flat row in [0,8192)
  const int b = row0 >> 11;

  // B staging: 17 groups of 8 rows (136 rows); wave w -> groups w, w+8;
  // wave 0 additionally group 16 (den rows = Vt rows 512..519).
  const unsigned short* pB0; const unsigned short* pB1; const unsigned short* pB2;
  int dOff0, dOff1, dOff2;
  {
    int I0 = wv,      rl0 = I0*8 + (lane >> 3), gk0 = (lane & 7) ^ (rl0 & 7);
    int I1 = wv + 8,  rl1 = I1*8 + (lane >> 3), gk1 = (lane & 7) ^ (rl1 & 7);
    pB0 = Vt + ((size_t)(b*VTR + ctq*128 + rl0))*NN + gk0*8;  dOff0 = I0*512;
    pB1 = Vt + ((size_t)(b*VTR + ctq*128 + rl1))*NN + gk1*8;  dOff1 = I1*512;
    int x = lane >> 3, gk2 = (lane & 7) ^ (x & 7);
    pB2 = Vt + ((size_t)(b*VTR + 512 + x))*NN + gk2*8;        dOff2 = 16*512;
  }

  // A staging: 512 threads, 2 rounds of 64 rows; thread handles row tid>>3,
  // k-slot tid&7 (8 ints -> 8 bf16 -> 1 ds_write_b128).
  const int* adjp = adj + (size_t)b*NN*NN + (size_t)(row0 & 2047)*NN
                    + (tid >> 3)*NN + (tid & 7)*8;
  unsigned short* sAp = &sA[tid >> 3][(tid & 7)*8];

  const int wi = wv >> 2, wc = wv & 3;           // 2 x 4 wave grid
  const int l31 = lane & 31, half = lane >> 5;
  f32x16 acc0 = {}; f32x16 acc1 = {}; f32x16 acc2 = {};
  const unsigned short* aRd0 = &sA[wi*64 +      l31][half*8];
  const unsigned short* aRd1 = &sA[wi*64 + 32 + l31][half*8];
  const int boff = (wc*32 + l31) * 64;

  for (int k0 = 0; k0 < NN; k0 += 64) {
    load_lds16(pB0 + k0, sB + dOff0);
    load_lds16(pB1 + k0, sB + dOff1);
    if (wv == 0) load_lds16(pB2 + k0, sB + dOff2);
#pragma unroll
    for (int rr = 0; rr < 2; ++rr) {
      const int* p = adjp + rr*64*NN + k0;
      int4 q0 = *(const int4*)p;
      int4 q1 = *(const int4*)(p + 4);
      uint4 u;
      u.x = (unsigned)(q0.x | (q0.y << 16)) * 0x3F80u;
      u.y = (unsigned)(q0.z | (q0.w << 16)) * 0x3F80u;
      u.z = (unsigned)(q1.x | (q1.y << 16)) * 0x3F80u;
      u.w = (unsigned)(q1.z | (q1.w << 16)) * 0x3F80u;
      *(uint4*)(sAp + rr*64*72) = u;
    }
    __syncthreads();
#pragma unroll
    for (int kb = 0; kb < 4; ++kb) {
      int kg = (kb*2 + half) ^ (lane & 7);
      bhalf8 bf = *(const bhalf8*)&sB[boff + kg*8];
      bhalf8 a0 = *(const bhalf8*)(aRd0 + kb*16);
      bhalf8 a1 = *(const bhalf8*)(aRd1 + kb*16);
      acc0 = __builtin_amdgcn_mfma_f32_32x32x16_bf16(a0, bf, acc0, 0, 0, 0);
      acc1 = __builtin_amdgcn_mfma_f32_32x32x16_bf16(a1, bf, acc1, 0, 0, 0);
      if (wc < 2) {
        bhalf8 bf2 = {};
        if (l31 < 8) bf2 = *(const bhalf8*)&sB[(128 + l31)*64 + kg*8];
        acc2 = __builtin_amdgcn_mfma_f32_32x32x16_bf16(wc ? a1 : a0, bf2, acc2, 0, 0, 0);
      }
    }
    __syncthreads();
  }

  // den extraction: wc<2 waves hold den for rows wi*64 + wc*32 + rmap;
  // output col (l31) == head; this pass needs heads 2*ctq and 2*ctq+1.
  const int hA = 2*ctq;
  if (wc < 2) {
    int rbase = wi*64 + wc*32;
    if (l31 == hA) {
#pragma unroll
      for (int reg = 0; reg < 16; ++reg)
        denL[rbase + (reg & 3) + 8*(reg >> 2) + 4*half][0] = acc2[reg];
    }
    if (l31 == hA + 1) {
#pragma unroll
      for (int reg = 0; reg < 16; ++reg)
        denL[rbase + (reg & 3) + 8*(reg >> 2) + 4*half][1] = acc2[reg];
    }
  }
  __syncthreads();

  // fused div + elu + raw-reshape remap store
  const int ib = row0 & 2047;
  const int c  = ctq*128 + wc*32 + l31;    // global data col 0..511
  const int d  = c & 63;
  const int h  = c >> 6;                   // = 2*ctq + (wc>>1)
  const int hloc = wc >> 1;
#pragma unroll
  for (int mi = 0; mi < 2; ++mi) {
    const f32x16 a = mi ? acc1 : acc0;
#pragma unroll
    for (int reg = 0; reg < 16; ++reg) {
      int il = wi*64 + mi*32 + (reg & 3) + 8*(reg >> 2) + 4*half;
      int i  = ib + il;
      float v = a[reg] / denL[il][hloc];
      v = v > 0.f ? v : expm1f(v);
      int n = (h << 8) | (i >> 3);
      int f = ((i & 7) << 6) | d;
      out[((size_t)b*NN + n)*FOUT + f] = v;
    }
  }
}

// ---------------------------------------------------------------------------
extern "C" void kernel_launch(void* const* d_in, const int* in_sizes, int n_in,
                              void* d_out, int out_size, void* d_ws, size_t ws_size,
                              hipStream_t stream)
{
  const float* hin = (const float*)d_in[0];   // h   f32 [4,2048,512]
  const int*   adj = (const int*)d_in[1];     // adj int32 [4,2048,2048]
  // d_in[2] = W_l : mathematically dead (softmax(el[i]+er[j]) == softmax(er[j]))
  const float* Wr  = (const float*)d_in[3];   // W_r f32 [512,512]
  const float* av  = (const float*)d_in[4];   // a   f32 [64,1]
  float* out = (float*)d_out;

  // Workspace overlays (peak ~34.9 MB):
  //   [0, 8.39M)      hHi   -> dead after gemm; overlaid by Vt
  //   [8.39M,16.78M)  hLo   -> dead after gemm
  //   [16.78M,17.30M) wTh   -> dead after gemm
  //   [17.30M,17.83M) wTl   -> dead after gemm
  //   [17.83M,26.2M)  Whr (bf16)
  //   [34.60M,34.86M) er
  //   [0, 8.52M)      Vt (bf16, 520 rows/batch) after gemm
  char* ws = (char*)d_ws;
  unsigned short* hHi = (unsigned short*)(ws);
  unsigned short* hLo = (unsigned short*)(ws + 8388608);
  unsigned short* wTh = (unsigned short*)(ws + 16777216);
  unsigned short* wTl = (unsigned short*)(ws + 17301504);
  unsigned short* Whr = (unsigned short*)(ws + 17825792);
  float* er   = (float*)(ws + 34603008);
  unsigned short* Vt = (unsigned short*)(ws);

  k_split_prep   <<<dim3(2112),    256, 0, stream>>>(hin, hHi, hLo, Wr, wTh, wTl);
  k_gemm_whr_mfma<<<dim3(512),     256, 0, stream>>>(hHi, hLo, wTh, wTl, Whr, av, er);
  k_softvt       <<<dim3(8, 8, 4), 256, 0, stream>>>(Whr, er, Vt);
  k_attn_out     <<<dim3(256),     512, 0, stream>>>(adj, Vt, out);
}